// Round 3
// baseline (264.241 us; speedup 1.0000x reference)
//
#include <hip/hip_runtime.h>
#include <math.h>

#define NIMG 8
#define NCLS 19
#define IMG_H 512
#define IMG_W 512
#define HW (IMG_H * IMG_W)
#define NQ (HW / 4)
#define GRIDX 256
#define NSLOT 80   // 0..18 seg_lpt, 19..37 seg_cnt, 38..56 att_lpt, 57..75 att_cnt,
                   // 76 bce_pos, 77 bce_neg, 78 pos_cnt, 79 neg_cnt

__device__ inline float wave_reduce_add(float v) {
    #pragma unroll
    for (int off = 32; off > 0; off >>= 1)
        v += __shfl_down(v, off, 64);
    return v;
}

// ---------------------------------------------------------------------------
// Single fused pass, per-block partial outputs (no global atomics, no memset).
// Phase A: all 19 class float4 loads issued before any use (MLP).
// Phase B: sum-exp, log-prob, per-(lane,class) LDS bins, BCE register sums.
// ---------------------------------------------------------------------------
__global__ __launch_bounds__(256, 4) void main_kernel(
    const float* __restrict__ segin,
    const float* __restrict__ edgein,
    const int* __restrict__ segmask,
    const int* __restrict__ edgemask,
    float* __restrict__ g_part)     // [NIMG][NSLOT][GRIDX]
{
    __shared__ float s_bins[4 * 64 * NCLS];   // [acc][lane][class], stride 19
    __shared__ float s_red[4][4];

    const int n = blockIdx.y;
    const int bx = blockIdx.x;
    const int tid = threadIdx.x;
    const int lane = tid & 63;
    const int wave = tid >> 6;

    for (int i = tid; i < 4 * 64 * NCLS; i += 256) s_bins[i] = 0.f;
    __syncthreads();

    float* bl_slpt = &s_bins[(0 * 64 + lane) * NCLS];
    float* bl_scnt = &s_bins[(1 * 64 + lane) * NCLS];
    float* bl_alpt = &s_bins[(2 * 64 + lane) * NCLS];
    float* bl_acnt = &s_bins[(3 * 64 + lane) * NCLS];

    const float4* segq  = (const float4*)(segin  + (size_t)n * NCLS * HW);
    const float4* edgeq = (const float4*)(edgein + (size_t)n * HW);
    const int4*   smq   = (const int4*)(segmask  + (size_t)n * HW);
    const int4*   emq   = (const int4*)(edgemask + (size_t)n * HW);

    float bp = 0.f, bn = 0.f, pc = 0.f, nc = 0.f;

    for (int q = bx * blockDim.x + tid; q < NQ; q += GRIDX * blockDim.x) {
        // ---- phase A: issue every load up front ----
        float4 xs[NCLS];
        #pragma unroll
        for (int c = 0; c < NCLS; c++)
            xs[c] = segq[(size_t)c * NQ + q];
        const int4 t4  = smq[q];
        const int4 te4 = emq[q];
        const float4 e4 = edgeq[q];

        // ---- phase B: compute ----
        const bool v0 = ((unsigned)t4.x < NCLS);
        const bool v1 = ((unsigned)t4.y < NCLS);
        const bool v2 = ((unsigned)t4.z < NCLS);
        const bool v3 = ((unsigned)t4.w < NCLS);
        const int tc0 = v0 ? t4.x : 0;
        const int tc1 = v1 ? t4.y : 0;
        const int tc2 = v2 ? t4.z : 0;
        const int tc3 = v3 ? t4.w : 0;

        float se0 = 0.f, se1 = 0.f, se2 = 0.f, se3 = 0.f;
        float xt0 = 0.f, xt1 = 0.f, xt2 = 0.f, xt3 = 0.f;
        #pragma unroll
        for (int c = 0; c < NCLS; c++) {
            se0 += __expf(xs[c].x);
            se1 += __expf(xs[c].y);
            se2 += __expf(xs[c].z);
            se3 += __expf(xs[c].w);
            xt0 = (c == tc0) ? xs[c].x : xt0;
            xt1 = (c == tc1) ? xs[c].y : xt1;
            xt2 = (c == tc2) ? xs[c].z : xt2;
            xt3 = (c == tc3) ? xs[c].w : xt3;
        }
        const float lp0 = xt0 - __logf(se0);
        const float lp1 = xt1 - __logf(se1);
        const float lp2 = xt2 - __logf(se2);
        const float lp3 = xt3 - __logf(se3);

        if (v0) { atomicAdd(&bl_slpt[tc0], lp0); atomicAdd(&bl_scnt[tc0], 1.f);
                  if (e4.x > 0.8f) { atomicAdd(&bl_alpt[tc0], lp0); atomicAdd(&bl_acnt[tc0], 1.f); } }
        if (v1) { atomicAdd(&bl_slpt[tc1], lp1); atomicAdd(&bl_scnt[tc1], 1.f);
                  if (e4.y > 0.8f) { atomicAdd(&bl_alpt[tc1], lp1); atomicAdd(&bl_acnt[tc1], 1.f); } }
        if (v2) { atomicAdd(&bl_slpt[tc2], lp2); atomicAdd(&bl_scnt[tc2], 1.f);
                  if (e4.z > 0.8f) { atomicAdd(&bl_alpt[tc2], lp2); atomicAdd(&bl_acnt[tc2], 1.f); } }
        if (v3) { atomicAdd(&bl_slpt[tc3], lp3); atomicAdd(&bl_scnt[tc3], 1.f);
                  if (e4.w > 0.8f) { atomicAdd(&bl_alpt[tc3], lp3); atomicAdd(&bl_acnt[tc3], 1.f); } }

        const float b0 = fmaxf(e4.x, 0.f) - e4.x * (float)te4.x + __logf(1.f + __expf(-fabsf(e4.x)));
        const float b1 = fmaxf(e4.y, 0.f) - e4.y * (float)te4.y + __logf(1.f + __expf(-fabsf(e4.y)));
        const float b2 = fmaxf(e4.z, 0.f) - e4.z * (float)te4.z + __logf(1.f + __expf(-fabsf(e4.z)));
        const float b3 = fmaxf(e4.w, 0.f) - e4.w * (float)te4.w + __logf(1.f + __expf(-fabsf(e4.w)));
        if (te4.x == 1) { bp += b0; pc += 1.f; } else if (te4.x == 0) { bn += b0; nc += 1.f; }
        if (te4.y == 1) { bp += b1; pc += 1.f; } else if (te4.y == 0) { bn += b1; nc += 1.f; }
        if (te4.z == 1) { bp += b2; pc += 1.f; } else if (te4.z == 0) { bn += b2; nc += 1.f; }
        if (te4.w == 1) { bp += b3; pc += 1.f; } else if (te4.w == 0) { bn += b3; nc += 1.f; }
    }

    // ---- BCE block reduction ----
    bp = wave_reduce_add(bp);
    bn = wave_reduce_add(bn);
    pc = wave_reduce_add(pc);
    nc = wave_reduce_add(nc);
    if (lane == 0) { s_red[0][wave] = bp; s_red[1][wave] = bn;
                     s_red[2][wave] = pc; s_red[3][wave] = nc; }
    __syncthreads();

    float* my_part = g_part + ((size_t)n * NSLOT) * GRIDX + bx;
    if (tid < 4 * NCLS) {
        const int acc = tid / NCLS;
        const int c = tid - acc * NCLS;
        float s = 0.f;
        #pragma unroll 8
        for (int l = 0; l < 64; l++)
            s += s_bins[(acc * 64 + l) * NCLS + c];
        my_part[(size_t)tid * GRIDX] = s;   // slot = acc*19 + c
    } else if (tid < 4 * NCLS + 4) {
        const int k = tid - 4 * NCLS;
        my_part[(size_t)(76 + k) * GRIDX] =
            s_red[k][0] + s_red[k][1] + s_red[k][2] + s_red[k][3];
    }
}

// ---------------------------------------------------------------------------
// Finalize: reduce per-block partials, weights from counts, 4 outputs.
// ---------------------------------------------------------------------------
__global__ __launch_bounds__(1024) void final_kernel(
    const float* __restrict__ g_part,
    float* __restrict__ out)
{
    __shared__ float s_acc[NIMG * NSLOT];
    __shared__ float s_seg[NIMG];
    __shared__ float s_att[NIMG];
    const int t = threadIdx.x;

    if (t < NIMG * NSLOT) {
        const float* p = g_part + (size_t)t * GRIDX;
        float s = 0.f;
        for (int b = 0; b < GRIDX; b++) s += p[b];
        s_acc[t] = s;
    }
    __syncthreads();

    if (t < NIMG) {
        const int n = t;
        const float* a = &s_acc[n * NSLOT];
        float tot = 0.f, tota = 0.f;
        for (int c = 0; c < NCLS; c++) { tot += a[19 + c]; tota += a[57 + c]; }
        tot  = fmaxf(tot, 1.0f);
        tota = fmaxf(tota, 1.0f);
        float wp = 0.f, wplp = 0.f, wpa = 0.f, wplpa = 0.f;
        for (int c = 0; c < NCLS; c++) {
            const float cs = a[19 + c];
            const float ca = a[57 + c];
            const float w  = (cs > 0.f) ? (2.0f - cs / tot ) : 1.0f;
            const float wa = (ca > 0.f) ? (2.0f - ca / tota) : 1.0f;
            wp    += w * cs;    wplp  += w * a[c];
            wpa   += wa * ca;   wplpa += wa * a[38 + c];
        }
        s_seg[n] = -wplp  / fmaxf(wp,  1e-12f);
        s_att[n] = -wplpa / fmaxf(wpa, 1e-12f);
    }
    __syncthreads();

    if (t == 0) {
        float seg = 0.f, att = 0.f, bpt = 0.f, bnt = 0.f, pct = 0.f, nct = 0.f;
        for (int n = 0; n < NIMG; n++) {
            seg += s_seg[n];
            att += s_att[n];
            bpt += s_acc[n * NSLOT + 76];
            bnt += s_acc[n * NSLOT + 77];
            pct += s_acc[n * NSLOT + 78];
            nct += s_acc[n * NSLOT + 79];
        }
        const float s = fmaxf(pct + nct, 1.0f);
        const float bce = (nct / s) * bpt + (pct / s) * bnt;
        out[0] = seg;
        out[1] = 20.0f * bce / (float)(NIMG * HW);
        out[2] = att;
        out[3] = 0.0f;
    }
}

extern "C" void kernel_launch(void* const* d_in, const int* in_sizes, int n_in,
                              void* d_out, int out_size, void* d_ws, size_t ws_size,
                              hipStream_t stream) {
    const float* segin    = (const float*)d_in[0];
    const float* edgein   = (const float*)d_in[1];
    const int*   segmask  = (const int*)d_in[2];
    const int*   edgemask = (const int*)d_in[3];
    float* out = (float*)d_out;

    float* g_part = (float*)d_ws;   // NIMG*NSLOT*GRIDX floats = 640 KB

    main_kernel<<<dim3(GRIDX, NIMG), 256, 0, stream>>>(
        segin, edgein, segmask, edgemask, g_part);
    final_kernel<<<1, 1024, 0, stream>>>(g_part, out);
}